// Round 2
// baseline (4764.278 us; speedup 1.0000x reference)
//
#include <hip/hip_runtime.h>
#include <hip/hip_bf16.h>

// SelfAttention (SAGAN-style): B=8, C=256, N=64*64=4096, Cp=32, fp32.
//   kernel 1 (qkv): x (B,C,N) -> qbuf (B,N,32), kbuf (B,N,32), vbuf (B,N,256) [=v^T]
//   kernel 2 (attn): flash-style online softmax; 512 thr/block, channel-split=2
// Workspace: (1M + 1M + 8M) floats = 40 MB.

constexpr int C  = 256;
constexpr int CP = 32;
constexpr int NPOS = 4096;
constexpr int NB = 8;

// ---------------------------------------------------------------------------
// QKV projection (unchanged from R1 — not the bottleneck).
// ---------------------------------------------------------------------------
__global__ __launch_bounds__(256) void qkv_kernel(
    const float* __restrict__ x,
    const float* __restrict__ Wq, const float* __restrict__ bq,
    const float* __restrict__ Wk, const float* __restrict__ bk,
    const float* __restrict__ Wv, const float* __restrict__ bv,
    float* __restrict__ qbuf, float* __restrict__ kbuf, float* __restrict__ vbuf)
{
    __shared__ float xl[C][64];    // 64 KB
    const int tid = threadIdx.x;
    const int b  = blockIdx.x >> 6;
    const int n0 = (blockIdx.x & 63) << 6;

    const float* xb = x + (size_t)b * C * NPOS + n0;
    for (int idx4 = tid; idx4 < C * 16; idx4 += 256) {
        int c = idx4 >> 4, j4 = idx4 & 15;
        float4 gg = *reinterpret_cast<const float4*>(xb + (size_t)c * NPOS + j4 * 4);
        *reinterpret_cast<float4*>(&xl[c][j4 * 4]) = gg;
    }
    __syncthreads();

    const int lane = tid & 63, g = tid >> 6;

    for (int grp = 0; grp < 5; ++grp) {
        const float* Wmat; const float* bias; float* ob; int r; int dd;
        if (grp == 0) {
            if (lane < 32) { Wmat = Wq; bias = bq; ob = qbuf; r = lane; }
            else           { Wmat = Wk; bias = bk; ob = kbuf; r = lane - 32; }
            dd = CP;
        } else {
            Wmat = Wv; bias = bv; ob = vbuf; r = (grp - 1) * 64 + lane; dd = C;
        }
        float acc[16];
        const float bval = bias[r];
        #pragma unroll
        for (int jj = 0; jj < 16; ++jj) acc[jj] = bval;

        const float* wrow = Wmat + (size_t)r * C;
        for (int c = 0; c < C; ++c) {
            float w = wrow[c];
            const float4* xv = reinterpret_cast<const float4*>(&xl[c][g * 16]);
            #pragma unroll
            for (int j4 = 0; j4 < 4; ++j4) {
                float4 xq = xv[j4];
                acc[j4*4+0] = fmaf(w, xq.x, acc[j4*4+0]);
                acc[j4*4+1] = fmaf(w, xq.y, acc[j4*4+1]);
                acc[j4*4+2] = fmaf(w, xq.z, acc[j4*4+2]);
                acc[j4*4+3] = fmaf(w, xq.w, acc[j4*4+3]);
            }
        }
        const size_t base = (size_t)b * NPOS + n0 + g * 16;
        #pragma unroll
        for (int jj = 0; jj < 16; ++jj)
            ob[(base + jj) * dd + r] = acc[jj];
    }
}

// ---------------------------------------------------------------------------
// Flash attention, restructured vs R1 (which spilled: acc[64]+q[32] > 64 VGPR).
//   512 threads (8 waves), channel-split=2: block = (b, qt, cs)
//   block covers queries [qt*64, qt*64+64), channels [cs*128, cs*128+128)
//   wave g owns 16 channels: cs*128 + g*16 .. +16 ; per-thread acc[16].
//   Scores (32 m-rows per tile) computed once per block: wave g does rows
//   g*4..g*4+4, shared via LDS. K/V addresses wave-uniform -> scalar loads.
//   Grid 1024 blocks, b = blockIdx&7 -> XCD-aware (one batch per XCD's L2).
// ---------------------------------------------------------------------------
__global__ __launch_bounds__(512, 4) void attn_kernel(
    const float* __restrict__ qbuf, const float* __restrict__ kbuf,
    const float* __restrict__ vbuf, const float* __restrict__ x,
    const float* __restrict__ gamma_p, float* __restrict__ out)
{
    __shared__ float sc[32][64];   // scores tile [m_local][n_local], 8 KB
    const int tid = threadIdx.x;
    const int b   = blockIdx.x & 7;        // XCD-aware swizzle
    const int tmp = blockIdx.x >> 3;
    const int cs  = tmp & 1;               // channel split index
    const int qt  = tmp >> 1;
    const int nl = tid & 63, g = tid >> 6; // g in 0..7
    const int n = qt * 64 + nl;
    const int ch0 = cs * 128 + g * 16;

    float4 q[8];
    const float4* qp = reinterpret_cast<const float4*>(qbuf + ((size_t)b * NPOS + n) * CP);
    #pragma unroll
    for (int i = 0; i < 8; ++i) q[i] = qp[i];

    float acc[16];
    #pragma unroll
    for (int i = 0; i < 16; ++i) acc[i] = 0.f;
    float mx = -1e30f, l = 0.f;

    const float* kb = kbuf + (size_t)b * NPOS * CP;
    const float* vb0 = vbuf + (size_t)b * NPOS * C + ch0;

    for (int mt = 0; mt < NPOS / 32; ++mt) {
        // phase 1: wave g computes score rows g*4 .. g*4+4 (once per block)
        #pragma unroll
        for (int ii = 0; ii < 4; ++ii) {
            const int mrow = mt * 32 + g * 4 + ii;
            const float4* kp = reinterpret_cast<const float4*>(kb + (size_t)mrow * CP);
            float s = 0.f;
            #pragma unroll
            for (int i = 0; i < 8; ++i) {
                float4 kv = kp[i];   // wave-uniform -> scalar load
                s = fmaf(q[i].x, kv.x, s); s = fmaf(q[i].y, kv.y, s);
                s = fmaf(q[i].z, kv.z, s); s = fmaf(q[i].w, kv.w, s);
            }
            sc[g * 4 + ii][nl] = s;
        }
        __syncthreads();

        // phase 2: online softmax + PV accumulate (16 channels per thread)
        float tm = -1e30f;
        #pragma unroll
        for (int i = 0; i < 32; ++i) tm = fmaxf(tm, sc[i][nl]);
        const float nm = fmaxf(mx, tm);
        const float scale = __expf(mx - nm);
        mx = nm;
        l *= scale;
        #pragma unroll
        for (int i = 0; i < 16; ++i) acc[i] *= scale;

        const float* vb = vb0 + (size_t)(mt * 32) * C;
        #pragma unroll 4
        for (int i = 0; i < 32; ++i) {
            const float p = __expf(sc[i][nl] - nm);
            l += p;
            const float4* vp = reinterpret_cast<const float4*>(vb + (size_t)i * C); // uniform
            #pragma unroll
            for (int c4 = 0; c4 < 4; ++c4) {
                float4 v = vp[c4];
                acc[c4*4+0] = fmaf(p, v.x, acc[c4*4+0]);
                acc[c4*4+1] = fmaf(p, v.y, acc[c4*4+1]);
                acc[c4*4+2] = fmaf(p, v.z, acc[c4*4+2]);
                acc[c4*4+3] = fmaf(p, v.w, acc[c4*4+3]);
            }
        }
        __syncthreads();   // before next tile overwrites sc
    }

    // epilogue: out = gamma * (acc/l) + x ; lanes n consecutive -> coalesced
    const float inv = 1.0f / l;
    const float gamma = *gamma_p;
    const float* xb = x + (size_t)b * C * NPOS;
    float* ob = out + (size_t)b * C * NPOS;
    #pragma unroll
    for (int jj = 0; jj < 16; ++jj) {
        const int c = ch0 + jj;
        const size_t idx = (size_t)c * NPOS + n;
        ob[idx] = gamma * (acc[jj] * inv) + xb[idx];
    }
}

extern "C" void kernel_launch(void* const* d_in, const int* in_sizes, int n_in,
                              void* d_out, int out_size, void* d_ws, size_t ws_size,
                              hipStream_t stream) {
    const float* x  = (const float*)d_in[0];
    const float* Wq = (const float*)d_in[1];
    const float* bq = (const float*)d_in[2];
    const float* Wk = (const float*)d_in[3];
    const float* bk = (const float*)d_in[4];
    const float* Wv = (const float*)d_in[5];
    const float* bv = (const float*)d_in[6];
    const float* gamma = (const float*)d_in[7];
    float* out = (float*)d_out;

    float* qbuf = (float*)d_ws;
    float* kbuf = qbuf + (size_t)NB * NPOS * CP;
    float* vbuf = kbuf + (size_t)NB * NPOS * CP;

    qkv_kernel<<<NB * (NPOS / 64), 256, 0, stream>>>(x, Wq, bq, Wk, bk, Wv, bv,
                                                     qbuf, kbuf, vbuf);
    // grid: (qt*2 + cs)*8 + b  -> blockIdx&7 = batch = XCD
    attn_kernel<<<NB * (NPOS / 64) * 2, 512, 0, stream>>>(qbuf, kbuf, vbuf, x, gamma, out);
}

// Round 3
// 1617.604 us; speedup vs baseline: 2.9453x; 2.9453x over previous
//
#include <hip/hip_runtime.h>
#include <hip/hip_bf16.h>

// SelfAttention (SAGAN-style): B=8, C=256, N=4096, Cp=32, fp32.
//   kernel 1 (qkv): x (B,C,N) -> qbuf (B,N,32), kbuf (B,N,32), vbuf (B,N,256)
//   kernel 2 (attn): LDS-tiled flash attention.
//     Block = 64 queries x 256 channels, 512 threads, grid 512 (2 blocks/CU).
//     Per m-tile (MT=32): stage K/V in LDS (reg-prefetched), scores tile in
//     LDS, per-lane online softmax, PV as register-tiled GEMM (4n x 8c /thr).

constexpr int C  = 256;
constexpr int CP = 32;
constexpr int NPOS = 4096;
constexpr int NB = 8;
constexpr int MT = 32;

// Raw barrier: LDS-drain only (no vmcnt drain -> global prefetch stays in
// flight across barriers; __syncthreads would drain vmcnt(0)).
__device__ __forceinline__ void bar_lds() {
    asm volatile("s_waitcnt lgkmcnt(0)\n\ts_barrier" ::: "memory");
}

// ---------------------------------------------------------------------------
// QKV projection (unchanged — attn dominates).
// ---------------------------------------------------------------------------
__global__ __launch_bounds__(256) void qkv_kernel(
    const float* __restrict__ x,
    const float* __restrict__ Wq, const float* __restrict__ bq,
    const float* __restrict__ Wk, const float* __restrict__ bk,
    const float* __restrict__ Wv, const float* __restrict__ bv,
    float* __restrict__ qbuf, float* __restrict__ kbuf, float* __restrict__ vbuf)
{
    __shared__ float xl[C][64];
    const int tid = threadIdx.x;
    const int b  = blockIdx.x >> 6;
    const int n0 = (blockIdx.x & 63) << 6;

    const float* xb = x + (size_t)b * C * NPOS + n0;
    for (int idx4 = tid; idx4 < C * 16; idx4 += 256) {
        int c = idx4 >> 4, j4 = idx4 & 15;
        float4 gg = *reinterpret_cast<const float4*>(xb + (size_t)c * NPOS + j4 * 4);
        *reinterpret_cast<float4*>(&xl[c][j4 * 4]) = gg;
    }
    __syncthreads();

    const int lane = tid & 63, g = tid >> 6;

    for (int grp = 0; grp < 5; ++grp) {
        const float* Wmat; const float* bias; float* ob; int r; int dd;
        if (grp == 0) {
            if (lane < 32) { Wmat = Wq; bias = bq; ob = qbuf; r = lane; }
            else           { Wmat = Wk; bias = bk; ob = kbuf; r = lane - 32; }
            dd = CP;
        } else {
            Wmat = Wv; bias = bv; ob = vbuf; r = (grp - 1) * 64 + lane; dd = C;
        }
        float acc[16];
        const float bval = bias[r];
        #pragma unroll
        for (int jj = 0; jj < 16; ++jj) acc[jj] = bval;

        const float* wrow = Wmat + (size_t)r * C;
        for (int c = 0; c < C; ++c) {
            float w = wrow[c];
            const float4* xv = reinterpret_cast<const float4*>(&xl[c][g * 16]);
            #pragma unroll
            for (int j4 = 0; j4 < 4; ++j4) {
                float4 xq = xv[j4];
                acc[j4*4+0] = fmaf(w, xq.x, acc[j4*4+0]);
                acc[j4*4+1] = fmaf(w, xq.y, acc[j4*4+1]);
                acc[j4*4+2] = fmaf(w, xq.z, acc[j4*4+2]);
                acc[j4*4+3] = fmaf(w, xq.w, acc[j4*4+3]);
            }
        }
        const size_t base = (size_t)b * NPOS + n0 + g * 16;
        #pragma unroll
        for (int jj = 0; jj < 16; ++jj)
            ob[(base + jj) * dd + r] = acc[jj];
    }
}

// ---------------------------------------------------------------------------
// Flash attention, LDS-tiled.
// ---------------------------------------------------------------------------
__global__ __launch_bounds__(512, 4) void attn_kernel(
    const float* __restrict__ qbuf, const float* __restrict__ kbuf,
    const float* __restrict__ vbuf, const float* __restrict__ x,
    const float* __restrict__ gamma_p, float* __restrict__ out)
{
    __shared__ float k_lds[MT][CP];      // 4 KB
    __shared__ float v_lds[MT][C];       // 32 KB (reused as o_lds in epilogue)
    __shared__ float sc_lds[MT][64];     // 8 KB: scores, then P
    __shared__ float scale_lds[64];      // per-n scale / final 1/l

    const int tid = threadIdx.x;
    const int b  = blockIdx.x & 7;       // XCD-aware: one batch per XCD L2
    const int qt = blockIdx.x >> 3;
    const int l  = tid & 63;             // lane: softmax column n = qt*64+l
    const int g  = tid >> 6;             // wave 0..7
    const int n0 = (tid & 15) * 4;       // PV tile: 4 queries
    const int c0 = (tid >> 4) * 8;       // PV tile: 8 channels

    // q row for column l (32 floats in registers)
    float4 q[8];
    {
        const float4* qp = reinterpret_cast<const float4*>(
            qbuf + ((size_t)b * NPOS + qt * 64 + l) * CP);
        #pragma unroll
        for (int i = 0; i < 8; ++i) q[i] = qp[i];
    }

    float acc[4][8];
    #pragma unroll
    for (int j = 0; j < 4; ++j)
        #pragma unroll
        for (int cc = 0; cc < 8; ++cc) acc[j][cc] = 0.f;
    float mx = -1e30f, lsum = 0.f;

    const float* kg = kbuf + (size_t)b * NPOS * CP;
    const float* vg = vbuf + (size_t)b * NPOS * C;

    // prologue: prefetch tile 0 into registers
    float2 kpre; float4 vpre[4];
    kpre = *reinterpret_cast<const float2*>(kg + tid * 2);
    #pragma unroll
    for (int j = 0; j < 4; ++j)
        vpre[j] = *reinterpret_cast<const float4*>(vg + tid * 4 + j * 2048);

    for (int mt = 0; mt < NPOS / MT; ++mt) {
        bar_lds();                       // b0: prev phase3 done reading LDS
        // write staged tile to LDS (contiguous per-lane -> conflict-free)
        *reinterpret_cast<float2*>(&k_lds[0][0] + tid * 2) = kpre;
        #pragma unroll
        for (int j = 0; j < 4; ++j)
            *reinterpret_cast<float4*>(&v_lds[0][0] + tid * 4 + j * 2048) = vpre[j];
        bar_lds();                       // b1: K,V visible

        // phase 1: wave g computes score rows g*4..g*4+3 for all 64 columns
        #pragma unroll
        for (int ii = 0; ii < 4; ++ii) {
            const int m = g * 4 + ii;
            const float4* kr = reinterpret_cast<const float4*>(&k_lds[m][0]); // uniform
            float s = 0.f;
            #pragma unroll
            for (int d4 = 0; d4 < 8; ++d4) {
                float4 kv = kr[d4];
                s = fmaf(q[d4].x, kv.x, s); s = fmaf(q[d4].y, kv.y, s);
                s = fmaf(q[d4].z, kv.z, s); s = fmaf(q[d4].w, kv.w, s);
            }
            sc_lds[m][l] = s;            // 2-way bank alias = free
        }
        bar_lds();                       // b2

        // softmax (per-lane column owner, redundant per wave)
        float tm = -1e30f;
        #pragma unroll
        for (int i = 0; i < MT; ++i) tm = fmaxf(tm, sc_lds[i][l]);
        const float nm = fmaxf(mx, tm);
        const float scale = __expf(mx - nm);
        float es = 0.f;
        #pragma unroll
        for (int i = 0; i < MT; ++i) es += __expf(sc_lds[i][l] - nm);
        lsum = lsum * scale + es;
        mx = nm;
        bar_lds();                       // b3: all sc reads done

        // overwrite sc with P (wave g owns rows g*4..g*4+3 of its column)
        #pragma unroll
        for (int ii = 0; ii < 4; ++ii) {
            const int m = g * 4 + ii;
            const float sv = sc_lds[m][l];
            sc_lds[m][l] = __expf(sv - nm);
        }
        if (g == 0) scale_lds[l] = scale;

        // prefetch next tile (latency hides under phase 3)
        if (mt + 1 < NPOS / MT) {
            const float* ks = kg + (size_t)(mt + 1) * MT * CP;
            const float* vs = vg + (size_t)(mt + 1) * MT * C;
            kpre = *reinterpret_cast<const float2*>(ks + tid * 2);
            #pragma unroll
            for (int j = 0; j < 4; ++j)
                vpre[j] = *reinterpret_cast<const float4*>(vs + tid * 4 + j * 2048);
        }
        bar_lds();                       // b4: P + scale visible

        // phase 3: rescale + PV GEMM (4n x 8c per thread)
        float sj[4];
        #pragma unroll
        for (int j = 0; j < 4; ++j) sj[j] = scale_lds[n0 + j];
        #pragma unroll
        for (int j = 0; j < 4; ++j)
            #pragma unroll
            for (int cc = 0; cc < 8; ++cc) acc[j][cc] *= sj[j];

        #pragma unroll 4
        for (int m = 0; m < MT; ++m) {
            const float4 p4 = *reinterpret_cast<const float4*>(&sc_lds[m][n0]);
            const float4 va = *reinterpret_cast<const float4*>(&v_lds[m][c0]);
            const float4 vb2 = *reinterpret_cast<const float4*>(&v_lds[m][c0 + 4]);
            const float pj[4] = {p4.x, p4.y, p4.z, p4.w};
            #pragma unroll
            for (int j = 0; j < 4; ++j) {
                const float p = pj[j];
                acc[j][0] = fmaf(p, va.x,  acc[j][0]);
                acc[j][1] = fmaf(p, va.y,  acc[j][1]);
                acc[j][2] = fmaf(p, va.z,  acc[j][2]);
                acc[j][3] = fmaf(p, va.w,  acc[j][3]);
                acc[j][4] = fmaf(p, vb2.x, acc[j][4]);
                acc[j][5] = fmaf(p, vb2.y, acc[j][5]);
                acc[j][6] = fmaf(p, vb2.z, acc[j][6]);
                acc[j][7] = fmaf(p, vb2.w, acc[j][7]);
            }
        }
    }

    // epilogue: out = gamma*(acc/l) + x, transposed through LDS for coalescing
    if (g == 0) scale_lds[l] = 1.0f / lsum;
    const float gamma = *gamma_p;
    const float* xb = x   + (size_t)b * C * NPOS;
    float*       ob = out + (size_t)b * C * NPOS;
    float* ols = &v_lds[0][0];           // 8192 floats = [128 c][64 n]

    #pragma unroll
    for (int r = 0; r < 2; ++r) {
        bar_lds();                       // phase3 / prev copy done; 1/l visible
        if ((tid >> 8) == r) {           // waves r*4..r*4+3 own this c-half
            float invl[4];
            #pragma unroll
            for (int j = 0; j < 4; ++j) invl[j] = scale_lds[n0 + j];
            const int crel = c0 - r * 128;
            #pragma unroll
            for (int cc = 0; cc < 8; ++cc) {
                float4 o;
                o.x = gamma * acc[0][cc] * invl[0];
                o.y = gamma * acc[1][cc] * invl[1];
                o.z = gamma * acc[2][cc] * invl[2];
                o.w = gamma * acc[3][cc] * invl[3];
                *reinterpret_cast<float4*>(ols + (crel + cc) * 64 + n0) = o;
            }
        }
        bar_lds();
        #pragma unroll
        for (int j2 = 0; j2 < 4; ++j2) {
            const int idx4 = tid + j2 * 512;       // float4 index in [128][64]
            const int c  = idx4 >> 4;
            const int nn = (idx4 & 15) * 4;
            const size_t gidx = ((size_t)(r * 128 + c)) * NPOS + qt * 64 + nn;
            float4 o = *reinterpret_cast<const float4*>(ols + idx4 * 4);
            const float4 xv = *reinterpret_cast<const float4*>(xb + gidx);
            o.x += xv.x; o.y += xv.y; o.z += xv.z; o.w += xv.w;
            *reinterpret_cast<float4*>(ob + gidx) = o;
        }
    }
}

extern "C" void kernel_launch(void* const* d_in, const int* in_sizes, int n_in,
                              void* d_out, int out_size, void* d_ws, size_t ws_size,
                              hipStream_t stream) {
    const float* x  = (const float*)d_in[0];
    const float* Wq = (const float*)d_in[1];
    const float* bq = (const float*)d_in[2];
    const float* Wk = (const float*)d_in[3];
    const float* bk = (const float*)d_in[4];
    const float* Wv = (const float*)d_in[5];
    const float* bv = (const float*)d_in[6];
    const float* gamma = (const float*)d_in[7];
    float* out = (float*)d_out;

    float* qbuf = (float*)d_ws;
    float* kbuf = qbuf + (size_t)NB * NPOS * CP;
    float* vbuf = kbuf + (size_t)NB * NPOS * CP;

    qkv_kernel<<<NB * (NPOS / 64), 256, 0, stream>>>(x, Wq, bq, Wk, bk, Wv, bv,
                                                     qbuf, kbuf, vbuf);
    attn_kernel<<<NB * (NPOS / 64), 512, 0, stream>>>(qbuf, kbuf, vbuf, x, gamma, out);
}

// Round 4
// 1562.847 us; speedup vs baseline: 3.0485x; 1.0350x over previous
//
#include <hip/hip_runtime.h>
#include <hip/hip_bf16.h>

// SelfAttention (SAGAN-style): B=8, C=256, N=4096, Cp=32, fp32.
//   kernel 1 (qkv): x (B,C,N) -> qbuf (B,N,32), kbuf (B,N,32), vbuf (B,N,256)
//   kernel 2 (attn): LDS-tiled flash attention.
//     Block = 64 queries x 256 channels, 512 threads, grid 512 (2 blocks/CU).
//     R4 change: amdgpu_waves_per_eu(2,4) -> 128-VGPR budget. R3 spilled 16
//     regs/thread/tile to scratch (WRITE_SIZE showed 2.09 GB vs 33.5 MB out).

constexpr int C  = 256;
constexpr int CP = 32;
constexpr int NPOS = 4096;
constexpr int NB = 8;
constexpr int MT = 32;

// Raw barrier: LDS-drain only (no vmcnt drain -> global prefetch stays in
// flight across barriers; __syncthreads would drain vmcnt(0)).
__device__ __forceinline__ void bar_lds() {
    asm volatile("s_waitcnt lgkmcnt(0)\n\ts_barrier" ::: "memory");
}

// ---------------------------------------------------------------------------
// QKV projection (unchanged — attn dominates).
// ---------------------------------------------------------------------------
__global__ __launch_bounds__(256) void qkv_kernel(
    const float* __restrict__ x,
    const float* __restrict__ Wq, const float* __restrict__ bq,
    const float* __restrict__ Wk, const float* __restrict__ bk,
    const float* __restrict__ Wv, const float* __restrict__ bv,
    float* __restrict__ qbuf, float* __restrict__ kbuf, float* __restrict__ vbuf)
{
    __shared__ float xl[C][64];
    const int tid = threadIdx.x;
    const int b  = blockIdx.x >> 6;
    const int n0 = (blockIdx.x & 63) << 6;

    const float* xb = x + (size_t)b * C * NPOS + n0;
    for (int idx4 = tid; idx4 < C * 16; idx4 += 256) {
        int c = idx4 >> 4, j4 = idx4 & 15;
        float4 gg = *reinterpret_cast<const float4*>(xb + (size_t)c * NPOS + j4 * 4);
        *reinterpret_cast<float4*>(&xl[c][j4 * 4]) = gg;
    }
    __syncthreads();

    const int lane = tid & 63, g = tid >> 6;

    for (int grp = 0; grp < 5; ++grp) {
        const float* Wmat; const float* bias; float* ob; int r; int dd;
        if (grp == 0) {
            if (lane < 32) { Wmat = Wq; bias = bq; ob = qbuf; r = lane; }
            else           { Wmat = Wk; bias = bk; ob = kbuf; r = lane - 32; }
            dd = CP;
        } else {
            Wmat = Wv; bias = bv; ob = vbuf; r = (grp - 1) * 64 + lane; dd = C;
        }
        float acc[16];
        const float bval = bias[r];
        #pragma unroll
        for (int jj = 0; jj < 16; ++jj) acc[jj] = bval;

        const float* wrow = Wmat + (size_t)r * C;
        for (int c = 0; c < C; ++c) {
            float w = wrow[c];
            const float4* xv = reinterpret_cast<const float4*>(&xl[c][g * 16]);
            #pragma unroll
            for (int j4 = 0; j4 < 4; ++j4) {
                float4 xq = xv[j4];
                acc[j4*4+0] = fmaf(w, xq.x, acc[j4*4+0]);
                acc[j4*4+1] = fmaf(w, xq.y, acc[j4*4+1]);
                acc[j4*4+2] = fmaf(w, xq.z, acc[j4*4+2]);
                acc[j4*4+3] = fmaf(w, xq.w, acc[j4*4+3]);
            }
        }
        const size_t base = (size_t)b * NPOS + n0 + g * 16;
        #pragma unroll
        for (int jj = 0; jj < 16; ++jj)
            ob[(base + jj) * dd + r] = acc[jj];
    }
}

// ---------------------------------------------------------------------------
// Flash attention, LDS-tiled. 128-VGPR budget via waves_per_eu(2,4).
// ---------------------------------------------------------------------------
__global__ __launch_bounds__(512)
__attribute__((amdgpu_waves_per_eu(2, 4)))
void attn_kernel(
    const float* __restrict__ qbuf, const float* __restrict__ kbuf,
    const float* __restrict__ vbuf, const float* __restrict__ x,
    const float* __restrict__ gamma_p, float* __restrict__ out)
{
    __shared__ float k_lds[MT][CP];      // 4 KB
    __shared__ float v_lds[MT][C];       // 32 KB (reused as o_lds in epilogue)
    __shared__ float sc_lds[MT][64];     // 8 KB: scores, then P
    __shared__ float scale_lds[64];      // per-n scale / final 1/l

    const int tid = threadIdx.x;
    const int b  = blockIdx.x & 7;       // XCD-aware: one batch per XCD L2
    const int qt = blockIdx.x >> 3;
    const int l  = tid & 63;             // lane: softmax column n = qt*64+l
    const int g  = tid >> 6;             // wave 0..7
    const int n0 = (tid & 15) * 4;       // PV tile: 4 queries
    const int c0 = (tid >> 4) * 8;       // PV tile: 8 channels

    // q row for column l (32 floats in registers)
    float4 q[8];
    {
        const float4* qp = reinterpret_cast<const float4*>(
            qbuf + ((size_t)b * NPOS + qt * 64 + l) * CP);
        #pragma unroll
        for (int i = 0; i < 8; ++i) q[i] = qp[i];
    }

    float acc[4][8];
    #pragma unroll
    for (int j = 0; j < 4; ++j)
        #pragma unroll
        for (int cc = 0; cc < 8; ++cc) acc[j][cc] = 0.f;
    float mx = -1e30f, lsum = 0.f;

    const float* kg = kbuf + (size_t)b * NPOS * CP;
    const float* vg = vbuf + (size_t)b * NPOS * C;

    // prologue: prefetch tile 0 into registers
    float2 kpre; float4 vpre[4];
    kpre = *reinterpret_cast<const float2*>(kg + tid * 2);
    #pragma unroll
    for (int j = 0; j < 4; ++j)
        vpre[j] = *reinterpret_cast<const float4*>(vg + tid * 4 + j * 2048);

    for (int mt = 0; mt < NPOS / MT; ++mt) {
        bar_lds();                       // b0: prev phase3 done reading LDS
        // write staged tile to LDS (contiguous per-lane -> conflict-free)
        *reinterpret_cast<float2*>(&k_lds[0][0] + tid * 2) = kpre;
        #pragma unroll
        for (int j = 0; j < 4; ++j)
            *reinterpret_cast<float4*>(&v_lds[0][0] + tid * 4 + j * 2048) = vpre[j];
        bar_lds();                       // b1: K,V visible

        // phase 1: wave g computes score rows g*4..g*4+3 for all 64 columns
        #pragma unroll
        for (int ii = 0; ii < 4; ++ii) {
            const int m = g * 4 + ii;
            const float4* kr = reinterpret_cast<const float4*>(&k_lds[m][0]); // uniform
            float s = 0.f;
            #pragma unroll
            for (int d4 = 0; d4 < 8; ++d4) {
                float4 kv = kr[d4];
                s = fmaf(q[d4].x, kv.x, s); s = fmaf(q[d4].y, kv.y, s);
                s = fmaf(q[d4].z, kv.z, s); s = fmaf(q[d4].w, kv.w, s);
            }
            sc_lds[m][l] = s;            // 2-way bank alias = free
        }
        bar_lds();                       // b2

        // softmax (per-lane column owner, redundant per wave)
        float tm = -1e30f;
        #pragma unroll
        for (int i = 0; i < MT; ++i) tm = fmaxf(tm, sc_lds[i][l]);
        const float nm = fmaxf(mx, tm);
        const float scale = __expf(mx - nm);
        float es = 0.f;
        #pragma unroll
        for (int i = 0; i < MT; ++i) es += __expf(sc_lds[i][l] - nm);
        lsum = lsum * scale + es;
        mx = nm;
        bar_lds();                       // b3: all sc reads done

        // overwrite sc with P (wave g owns rows g*4..g*4+3 of its column)
        #pragma unroll
        for (int ii = 0; ii < 4; ++ii) {
            const int m = g * 4 + ii;
            const float sv = sc_lds[m][l];
            sc_lds[m][l] = __expf(sv - nm);
        }
        if (g == 0) scale_lds[l] = scale;

        // prefetch next tile (latency hides under phase 3)
        if (mt + 1 < NPOS / MT) {
            const float* ks = kg + (size_t)(mt + 1) * MT * CP;
            const float* vs = vg + (size_t)(mt + 1) * MT * C;
            kpre = *reinterpret_cast<const float2*>(ks + tid * 2);
            #pragma unroll
            for (int j = 0; j < 4; ++j)
                vpre[j] = *reinterpret_cast<const float4*>(vs + tid * 4 + j * 2048);
        }
        bar_lds();                       // b4: P + scale visible

        // phase 3: rescale + PV GEMM (4n x 8c per thread)
        float sj[4];
        #pragma unroll
        for (int j = 0; j < 4; ++j) sj[j] = scale_lds[n0 + j];
        #pragma unroll
        for (int j = 0; j < 4; ++j)
            #pragma unroll
            for (int cc = 0; cc < 8; ++cc) acc[j][cc] *= sj[j];

        #pragma unroll 4
        for (int m = 0; m < MT; ++m) {
            const float4 p4 = *reinterpret_cast<const float4*>(&sc_lds[m][n0]);
            const float4 va = *reinterpret_cast<const float4*>(&v_lds[m][c0]);
            const float4 vb2 = *reinterpret_cast<const float4*>(&v_lds[m][c0 + 4]);
            const float pj[4] = {p4.x, p4.y, p4.z, p4.w};
            #pragma unroll
            for (int j = 0; j < 4; ++j) {
                const float p = pj[j];
                acc[j][0] = fmaf(p, va.x,  acc[j][0]);
                acc[j][1] = fmaf(p, va.y,  acc[j][1]);
                acc[j][2] = fmaf(p, va.z,  acc[j][2]);
                acc[j][3] = fmaf(p, va.w,  acc[j][3]);
                acc[j][4] = fmaf(p, vb2.x, acc[j][4]);
                acc[j][5] = fmaf(p, vb2.y, acc[j][5]);
                acc[j][6] = fmaf(p, vb2.z, acc[j][6]);
                acc[j][7] = fmaf(p, vb2.w, acc[j][7]);
            }
        }
    }

    // epilogue: out = gamma*(acc/l) + x, transposed through LDS for coalescing
    if (g == 0) scale_lds[l] = 1.0f / lsum;
    const float gamma = *gamma_p;
    const float* xb = x   + (size_t)b * C * NPOS;
    float*       ob = out + (size_t)b * C * NPOS;
    float* ols = &v_lds[0][0];           // 8192 floats = [128 c][64 n]

    #pragma unroll
    for (int r = 0; r < 2; ++r) {
        bar_lds();                       // phase3 / prev copy done; 1/l visible
        if ((tid >> 8) == r) {           // waves r*4..r*4+3 own this c-half
            float invl[4];
            #pragma unroll
            for (int j = 0; j < 4; ++j) invl[j] = scale_lds[n0 + j];
            const int crel = c0 - r * 128;
            #pragma unroll
            for (int cc = 0; cc < 8; ++cc) {
                float4 o;
                o.x = gamma * acc[0][cc] * invl[0];
                o.y = gamma * acc[1][cc] * invl[1];
                o.z = gamma * acc[2][cc] * invl[2];
                o.w = gamma * acc[3][cc] * invl[3];
                *reinterpret_cast<float4*>(ols + (crel + cc) * 64 + n0) = o;
            }
        }
        bar_lds();
        #pragma unroll
        for (int j2 = 0; j2 < 4; ++j2) {
            const int idx4 = tid + j2 * 512;       // float4 index in [128][64]
            const int c  = idx4 >> 4;
            const int nn = (idx4 & 15) * 4;
            const size_t gidx = ((size_t)(r * 128 + c)) * NPOS + qt * 64 + nn;
            float4 o = *reinterpret_cast<const float4*>(ols + idx4 * 4);
            const float4 xv = *reinterpret_cast<const float4*>(xb + gidx);
            o.x += xv.x; o.y += xv.y; o.z += xv.z; o.w += xv.w;
            *reinterpret_cast<float4*>(ob + gidx) = o;
        }
    }
}

extern "C" void kernel_launch(void* const* d_in, const int* in_sizes, int n_in,
                              void* d_out, int out_size, void* d_ws, size_t ws_size,
                              hipStream_t stream) {
    const float* x  = (const float*)d_in[0];
    const float* Wq = (const float*)d_in[1];
    const float* bq = (const float*)d_in[2];
    const float* Wk = (const float*)d_in[3];
    const float* bk = (const float*)d_in[4];
    const float* Wv = (const float*)d_in[5];
    const float* bv = (const float*)d_in[6];
    const float* gamma = (const float*)d_in[7];
    float* out = (float*)d_out;

    float* qbuf = (float*)d_ws;
    float* kbuf = qbuf + (size_t)NB * NPOS * CP;
    float* vbuf = kbuf + (size_t)NB * NPOS * CP;

    qkv_kernel<<<NB * (NPOS / 64), 256, 0, stream>>>(x, Wq, bq, Wk, bk, Wv, bv,
                                                     qbuf, kbuf, vbuf);
    attn_kernel<<<NB * (NPOS / 64), 512, 0, stream>>>(qbuf, kbuf, vbuf, x, gamma, out);
}

// Round 5
// 1096.559 us; speedup vs baseline: 4.3448x; 1.4252x over previous
//
#include <hip/hip_runtime.h>
#include <hip/hip_bf16.h>

// SelfAttention (SAGAN-style): B=8, C=256, N=4096, Cp=32, fp32.
//   kernel 1 (qkv): x (B,C,N) -> qbuf (B,N,32), kbuf (B,N,32), vbuf (B,N,256)
//   kernel 2 (attn): LDS-tiled flash attention.
//     R5: global_load_lds staging (no staging VGPRs -> no spill), per-wave V
//     slices (no barrier for V), wave-parallel softmax (was 8x redundant),
//     unroll 2 in PV (bounded reg pressure). 3 barriers/tile (was 5).

constexpr int C  = 256;
constexpr int CP = 32;
constexpr int NPOS = 4096;
constexpr int NB = 8;
constexpr int MT = 32;
constexpr int NT = NPOS / MT;   // 128

__device__ __forceinline__ void bar_lds() {
    asm volatile("s_waitcnt lgkmcnt(0)\n\ts_barrier" ::: "memory");
}
__device__ __forceinline__ void wait_vm0() {
    asm volatile("s_waitcnt vmcnt(0)" ::: "memory");
}
// async global->LDS, 16B per lane. LDS dest wave-uniform base + lane*16;
// global src per-lane.
__device__ __forceinline__ void gl_lds16(const float* gsrc, float* ldst) {
    typedef const __attribute__((address_space(1))) void* gp_t;
    typedef __attribute__((address_space(3))) void* lp_t;
    __builtin_amdgcn_global_load_lds((gp_t)gsrc, (lp_t)ldst, 16, 0, 0);
}

// ---------------------------------------------------------------------------
// QKV projection (unchanged — attn dominates).
// ---------------------------------------------------------------------------
__global__ __launch_bounds__(256) void qkv_kernel(
    const float* __restrict__ x,
    const float* __restrict__ Wq, const float* __restrict__ bq,
    const float* __restrict__ Wk, const float* __restrict__ bk,
    const float* __restrict__ Wv, const float* __restrict__ bv,
    float* __restrict__ qbuf, float* __restrict__ kbuf, float* __restrict__ vbuf)
{
    __shared__ float xl[C][64];
    const int tid = threadIdx.x;
    const int b  = blockIdx.x >> 6;
    const int n0 = (blockIdx.x & 63) << 6;

    const float* xb = x + (size_t)b * C * NPOS + n0;
    for (int idx4 = tid; idx4 < C * 16; idx4 += 256) {
        int c = idx4 >> 4, j4 = idx4 & 15;
        float4 gg = *reinterpret_cast<const float4*>(xb + (size_t)c * NPOS + j4 * 4);
        *reinterpret_cast<float4*>(&xl[c][j4 * 4]) = gg;
    }
    __syncthreads();

    const int lane = tid & 63, g = tid >> 6;

    for (int grp = 0; grp < 5; ++grp) {
        const float* Wmat; const float* bias; float* ob; int r; int dd;
        if (grp == 0) {
            if (lane < 32) { Wmat = Wq; bias = bq; ob = qbuf; r = lane; }
            else           { Wmat = Wk; bias = bk; ob = kbuf; r = lane - 32; }
            dd = CP;
        } else {
            Wmat = Wv; bias = bv; ob = vbuf; r = (grp - 1) * 64 + lane; dd = C;
        }
        float acc[16];
        const float bval = bias[r];
        #pragma unroll
        for (int jj = 0; jj < 16; ++jj) acc[jj] = bval;

        const float* wrow = Wmat + (size_t)r * C;
        for (int c = 0; c < C; ++c) {
            float w = wrow[c];
            const float4* xv = reinterpret_cast<const float4*>(&xl[c][g * 16]);
            #pragma unroll
            for (int j4 = 0; j4 < 4; ++j4) {
                float4 xq = xv[j4];
                acc[j4*4+0] = fmaf(w, xq.x, acc[j4*4+0]);
                acc[j4*4+1] = fmaf(w, xq.y, acc[j4*4+1]);
                acc[j4*4+2] = fmaf(w, xq.z, acc[j4*4+2]);
                acc[j4*4+3] = fmaf(w, xq.w, acc[j4*4+3]);
            }
        }
        const size_t base = (size_t)b * NPOS + n0 + g * 16;
        #pragma unroll
        for (int jj = 0; jj < 16; ++jj)
            ob[(base + jj) * dd + r] = acc[jj];
    }
}

// ---------------------------------------------------------------------------
// Flash attention.
//   512 threads (8 waves), block = 64 queries x 256 channels, grid 512.
//   Lane l owns softmax column n = qt*64+l; wave g owns score rows g*4..g*4+3
//   and V channel slice [g*32, g*32+32).
// ---------------------------------------------------------------------------
__global__ __launch_bounds__(512)
__attribute__((amdgpu_waves_per_eu(4)))
void attn_kernel(
    const float* __restrict__ qbuf, const float* __restrict__ kbuf,
    const float* __restrict__ vbuf, const float* __restrict__ x,
    const float* __restrict__ gamma_p, float* __restrict__ out)
{
    __shared__ float k_lds[2][MT][CP];   // 8 KB double-buffered K tile
    __shared__ float v_lds[8][MT][32];   // 32 KB: per-wave V slice (reused as ols)
    __shared__ float p_lds[MT][64];      // 8 KB: P tile [m][n]
    __shared__ float pmx[8][64];         // 2 KB: per-wave partial max
    __shared__ float psm[8][64];         // 2 KB: per-wave partial expsum
    __shared__ float scale_lds[64];      // per-column rescale / final 1/l

    const int tid = threadIdx.x;
    const int b  = blockIdx.x & 7;       // XCD-aware: one batch per XCD L2
    const int qt = blockIdx.x >> 3;
    const int l  = tid & 63;             // lane
    const int g  = tid >> 6;             // wave 0..7
    const int n0 = (tid & 15) * 4;       // PV: 4 query columns
    const int c0r = ((tid >> 4) & 3) * 8;// PV: channel offset within wave slice

    const float* kg = kbuf + (size_t)b * NPOS * CP;
    const float* vg = vbuf + (size_t)b * NPOS * C;

    // q row for column l (32 floats in registers)
    float4 q[8];
    {
        const float4* qp = reinterpret_cast<const float4*>(
            qbuf + ((size_t)b * NPOS + qt * 64 + l) * CP);
        #pragma unroll
        for (int i = 0; i < 8; ++i) q[i] = qp[i];
    }

    float acc[4][8];
    #pragma unroll
    for (int j = 0; j < 4; ++j)
        #pragma unroll
        for (int cc = 0; cc < 8; ++cc) acc[j][cc] = 0.f;
    float mx = -1e30f, lsum = 0.f;

    // prologue: stage tile 0 (K by waves 0-3; V slice by owning wave)
    if (g < 4)
        gl_lds16(kg + g * 256 + l * 4, &k_lds[0][0][0] + g * 256);
    #pragma unroll
    for (int cch = 0; cch < 4; ++cch)
        gl_lds16(vg + (size_t)(cch * 8 + (l >> 3)) * C + g * 32 + (l & 7) * 4,
                 &v_lds[g][cch * 8][0]);

    for (int t = 0; t < NT; ++t) {
        const int buf = t & 1;
        wait_vm0();                      // K(t) + own V(t) arrived
        bar_lds();                       // b1: K visible to all; p_lds free

        // issue K(t+1) into other buffer (waves 0-3, one instr each)
        if (g < 4 && t + 1 < NT)
            gl_lds16(kg + (size_t)(t + 1) * MT * CP + g * 256 + l * 4,
                     &k_lds[buf ^ 1][0][0] + g * 256);

        // phase 1: QK^T — wave g computes rows g*4..g*4+3 for its column l
        float s[4];
        #pragma unroll
        for (int ii = 0; ii < 4; ++ii) {
            const float4* kr = reinterpret_cast<const float4*>(
                &k_lds[buf][g * 4 + ii][0]);          // wave-uniform broadcast
            float sv = 0.f;
            #pragma unroll
            for (int d4 = 0; d4 < 8; ++d4) {
                float4 kv = kr[d4];
                sv = fmaf(q[d4].x, kv.x, sv); sv = fmaf(q[d4].y, kv.y, sv);
                sv = fmaf(q[d4].z, kv.z, sv); sv = fmaf(q[d4].w, kv.w, sv);
            }
            s[ii] = sv;
        }
        pmx[g][l] = fmaxf(fmaxf(s[0], s[1]), fmaxf(s[2], s[3]));
        bar_lds();                       // b2: partial maxes visible

        // softmax A: global max, exp own rows, partial sum
        float tm = pmx[0][l];
        #pragma unroll
        for (int gg = 1; gg < 8; ++gg) tm = fmaxf(tm, pmx[gg][l]);
        const float nm = fmaxf(mx, tm);
        const float scale = __expf(mx - nm);
        float p[4];
        float ps = 0.f;
        #pragma unroll
        for (int ii = 0; ii < 4; ++ii) {
            p[ii] = __expf(s[ii] - nm);
            ps += p[ii];
            p_lds[g * 4 + ii][l] = p[ii];
        }
        psm[g][l] = ps;
        if (g == 0) scale_lds[l] = scale;
        mx = nm;
        bar_lds();                       // b3: P, psums, scale visible

        // softmax B: total expsum for column l
        float es = psm[0][l];
        #pragma unroll
        for (int gg = 1; gg < 8; ++gg) es += psm[gg][l];
        lsum = lsum * scale + es;

        // phase 3: rescale + PV GEMM (4 queries x 8 channels per thread)
        float sj[4];
        #pragma unroll
        for (int j = 0; j < 4; ++j) sj[j] = scale_lds[n0 + j];
        #pragma unroll
        for (int j = 0; j < 4; ++j)
            #pragma unroll
            for (int cc = 0; cc < 8; ++cc) acc[j][cc] *= sj[j];

        const float* vw = &v_lds[g][0][0];
        #pragma unroll 2
        for (int m = 0; m < 16; ++m) {
            const float4 p4 = *reinterpret_cast<const float4*>(&p_lds[m][n0]);
            const float4 va = *reinterpret_cast<const float4*>(vw + m * 32 + c0r);
            const float4 vb2 = *reinterpret_cast<const float4*>(vw + m * 32 + c0r + 4);
            const float pj[4] = {p4.x, p4.y, p4.z, p4.w};
            #pragma unroll
            for (int j = 0; j < 4; ++j) {
                const float pp = pj[j];
                acc[j][0] = fmaf(pp, va.x,  acc[j][0]);
                acc[j][1] = fmaf(pp, va.y,  acc[j][1]);
                acc[j][2] = fmaf(pp, va.z,  acc[j][2]);
                acc[j][3] = fmaf(pp, va.w,  acc[j][3]);
                acc[j][4] = fmaf(pp, vb2.x, acc[j][4]);
                acc[j][5] = fmaf(pp, vb2.y, acc[j][5]);
                acc[j][6] = fmaf(pp, vb2.z, acc[j][6]);
                acc[j][7] = fmaf(pp, vb2.w, acc[j][7]);
            }
        }
        // rows 0..15 of this wave's V slice consumed -> refill them for t+1
        if (t + 1 < NT) {
            #pragma unroll
            for (int cch = 0; cch < 2; ++cch)
                gl_lds16(vg + (size_t)((t + 1) * MT + cch * 8 + (l >> 3)) * C
                            + g * 32 + (l & 7) * 4,
                         &v_lds[g][cch * 8][0]);
        }
        #pragma unroll 2
        for (int m = 16; m < 32; ++m) {
            const float4 p4 = *reinterpret_cast<const float4*>(&p_lds[m][n0]);
            const float4 va = *reinterpret_cast<const float4*>(vw + m * 32 + c0r);
            const float4 vb2 = *reinterpret_cast<const float4*>(vw + m * 32 + c0r + 4);
            const float pj[4] = {p4.x, p4.y, p4.z, p4.w};
            #pragma unroll
            for (int j = 0; j < 4; ++j) {
                const float pp = pj[j];
                acc[j][0] = fmaf(pp, va.x,  acc[j][0]);
                acc[j][1] = fmaf(pp, va.y,  acc[j][1]);
                acc[j][2] = fmaf(pp, va.z,  acc[j][2]);
                acc[j][3] = fmaf(pp, va.w,  acc[j][3]);
                acc[j][4] = fmaf(pp, vb2.x, acc[j][4]);
                acc[j][5] = fmaf(pp, vb2.y, acc[j][5]);
                acc[j][6] = fmaf(pp, vb2.z, acc[j][6]);
                acc[j][7] = fmaf(pp, vb2.w, acc[j][7]);
            }
        }
        if (t + 1 < NT) {
            #pragma unroll
            for (int cch = 2; cch < 4; ++cch)
                gl_lds16(vg + (size_t)((t + 1) * MT + cch * 8 + (l >> 3)) * C
                            + g * 32 + (l & 7) * 4,
                         &v_lds[g][cch * 8][0]);
        }
    }

    // epilogue: out = gamma*(acc/l) + x, transposed through LDS (reuse v_lds)
    if (g == 0) scale_lds[l] = 1.0f / lsum;
    const float gamma = *gamma_p;
    const float* xb = x   + (size_t)b * C * NPOS;
    float*       ob = out + (size_t)b * C * NPOS;
    float* ols = &v_lds[0][0][0];        // 8192 floats = [128 c][64 n]
    const int c0 = (tid >> 4) * 8;       // global channel of this thread's acc

    #pragma unroll
    for (int r = 0; r < 2; ++r) {
        bar_lds();                       // phase3 / prev copy done; 1/l visible
        if ((tid >> 8) == r) {           // waves r*4..r*4+3 own this c-half
            float invl[4];
            #pragma unroll
            for (int j = 0; j < 4; ++j) invl[j] = scale_lds[n0 + j];
            const int crel = c0 - r * 128;
            #pragma unroll
            for (int cc = 0; cc < 8; ++cc) {
                float4 o;
                o.x = gamma * acc[0][cc] * invl[0];
                o.y = gamma * acc[1][cc] * invl[1];
                o.z = gamma * acc[2][cc] * invl[2];
                o.w = gamma * acc[3][cc] * invl[3];
                *reinterpret_cast<float4*>(ols + (crel + cc) * 64 + n0) = o;
            }
        }
        bar_lds();
        #pragma unroll
        for (int j2 = 0; j2 < 4; ++j2) {
            const int idx4 = tid + j2 * 512;       // float4 index in [128][64]
            const int c  = idx4 >> 4;
            const int nn = (idx4 & 15) * 4;
            const size_t gidx = ((size_t)(r * 128 + c)) * NPOS + qt * 64 + nn;
            float4 o = *reinterpret_cast<const float4*>(ols + idx4 * 4);
            const float4 xv = *reinterpret_cast<const float4*>(xb + gidx);
            o.x += xv.x; o.y += xv.y; o.z += xv.z; o.w += xv.w;
            *reinterpret_cast<float4*>(ob + gidx) = o;
        }
    }
}

extern "C" void kernel_launch(void* const* d_in, const int* in_sizes, int n_in,
                              void* d_out, int out_size, void* d_ws, size_t ws_size,
                              hipStream_t stream) {
    const float* x  = (const float*)d_in[0];
    const float* Wq = (const float*)d_in[1];
    const float* bq = (const float*)d_in[2];
    const float* Wk = (const float*)d_in[3];
    const float* bk = (const float*)d_in[4];
    const float* Wv = (const float*)d_in[5];
    const float* bv = (const float*)d_in[6];
    const float* gamma = (const float*)d_in[7];
    float* out = (float*)d_out;

    float* qbuf = (float*)d_ws;
    float* kbuf = qbuf + (size_t)NB * NPOS * CP;
    float* vbuf = kbuf + (size_t)NB * NPOS * CP;

    qkv_kernel<<<NB * (NPOS / 64), 256, 0, stream>>>(x, Wq, bq, Wk, bk, Wv, bv,
                                                     qbuf, kbuf, vbuf);
    attn_kernel<<<NB * (NPOS / 64), 512, 0, stream>>>(qbuf, kbuf, vbuf, x, gamma, out);
}

// Round 7
// 388.315 us; speedup vs baseline: 12.2691x; 2.8239x over previous
//
#include <hip/hip_runtime.h>
#include <hip/hip_bf16.h>

// SelfAttention (SAGAN-style): B=8, C=256, N=4096, Cp=32, fp32 in/out.
//   kernel 1 (qkv): x -> qbuf (B,N,32) f32, kbuf (B,N,32) f32,
//                   vT (B,C,N) bf16 (transposed, single precision: harness
//                   threshold is 0.115 bf16-granular).
//   kernel 2 (attn): flash attention; QK^T + softmax fp32 (R5-proven),
//                   PV via mfma_f32_16x16x32_bf16 computing O^T tiles.
// R7 vs R6: fragment layout fixed to the VERIFIED contiguous-k form
//   (A/B lane l holds k=(l>>4)*8+j, one b128 per fragment; m92/m97 ladder),
//   V double-buffered in LDS (no mid-loop refill hazard), O^T orientation
//   so the epilogue is direct coalesced stores (no LDS transpose).

constexpr int C  = 256;
constexpr int CP = 32;
constexpr int NPOS = 4096;
constexpr int NB = 8;
constexpr int MT = 32;
constexpr int NT = NPOS / MT;   // 128

typedef __attribute__((ext_vector_type(4))) float  f32x4;
typedef __attribute__((ext_vector_type(4))) short  bf16x4;
typedef __attribute__((ext_vector_type(8))) short  bf16x8;

__device__ __forceinline__ void bar_lds() {
    asm volatile("s_waitcnt lgkmcnt(0)\n\ts_barrier" ::: "memory");
}
__device__ __forceinline__ void wait_vm0() {
    asm volatile("s_waitcnt vmcnt(0)" ::: "memory");
}
__device__ __forceinline__ void gl_lds16(const void* gsrc, void* ldst) {
    typedef const __attribute__((address_space(1))) void* gp_t;
    typedef __attribute__((address_space(3))) void* lp_t;
    __builtin_amdgcn_global_load_lds((gp_t)gsrc, (lp_t)ldst, 16, 0, 0);
}
__device__ __forceinline__ short f2bf(float f) {
    __hip_bfloat16 h = __float2bfloat16(f);
    return __builtin_bit_cast(short, h);
}

// ---------------------------------------------------------------------------
// QKV projection. Q/K f32 [b][n][d]; V -> bf16 transposed [b][c][n].
// ---------------------------------------------------------------------------
__global__ __launch_bounds__(256) void qkv_kernel(
    const float* __restrict__ x,
    const float* __restrict__ Wq, const float* __restrict__ bq,
    const float* __restrict__ Wk, const float* __restrict__ bk,
    const float* __restrict__ Wv, const float* __restrict__ bv,
    float* __restrict__ qbuf, float* __restrict__ kbuf,
    __hip_bfloat16* __restrict__ vT)
{
    __shared__ float xl[C][64];
    const int tid = threadIdx.x;
    const int b  = blockIdx.x >> 6;
    const int n0 = (blockIdx.x & 63) << 6;

    const float* xb = x + (size_t)b * C * NPOS + n0;
    for (int idx4 = tid; idx4 < C * 16; idx4 += 256) {
        int c = idx4 >> 4, j4 = idx4 & 15;
        float4 gg = *reinterpret_cast<const float4*>(xb + (size_t)c * NPOS + j4 * 4);
        *reinterpret_cast<float4*>(&xl[c][j4 * 4]) = gg;
    }
    __syncthreads();

    const int lane = tid & 63, g = tid >> 6;

    for (int grp = 0; grp < 5; ++grp) {
        const float* Wmat; const float* bias; int r;
        if (grp == 0) {
            if (lane < 32) { Wmat = Wq; bias = bq; r = lane; }
            else           { Wmat = Wk; bias = bk; r = lane - 32; }
        } else {
            Wmat = Wv; bias = bv; r = (grp - 1) * 64 + lane;
        }
        float acc[16];
        const float bval = bias[r];
        #pragma unroll
        for (int jj = 0; jj < 16; ++jj) acc[jj] = bval;

        const float* wrow = Wmat + (size_t)r * C;
        for (int c = 0; c < C; ++c) {
            float w = wrow[c];
            const float4* xv = reinterpret_cast<const float4*>(&xl[c][g * 16]);
            #pragma unroll
            for (int j4 = 0; j4 < 4; ++j4) {
                float4 xq = xv[j4];
                acc[j4*4+0] = fmaf(w, xq.x, acc[j4*4+0]);
                acc[j4*4+1] = fmaf(w, xq.y, acc[j4*4+1]);
                acc[j4*4+2] = fmaf(w, xq.z, acc[j4*4+2]);
                acc[j4*4+3] = fmaf(w, xq.w, acc[j4*4+3]);
            }
        }
        if (grp == 0) {
            float* ob = (lane < 32) ? qbuf : kbuf;
            const size_t base = (size_t)b * NPOS + n0 + g * 16;
            #pragma unroll
            for (int jj = 0; jj < 16; ++jj)
                ob[(base + jj) * CP + r] = acc[jj];
        } else {
            // vT[b][r][n0 + g*16 + jj], 16 contiguous bf16 = 2x 16B stores
            bf16x8 w0, w1;
            #pragma unroll
            for (int jj = 0; jj < 8; ++jj) { w0[jj] = f2bf(acc[jj]); w1[jj] = f2bf(acc[8 + jj]); }
            __hip_bfloat16* vp = vT + ((size_t)b * C + r) * NPOS + n0 + g * 16;
            *reinterpret_cast<bf16x8*>(vp)     = w0;
            *reinterpret_cast<bf16x8*>(vp + 8) = w1;
        }
    }
}

// ---------------------------------------------------------------------------
// Flash attention with MFMA PV (O^T orientation).
//   512 threads (8 waves), block = 64 queries x 256 channels, grid 512.
//   Lane l owns softmax column n = qt*64+l; wave g owns score rows g*4..+3
//   and channels [g*32, g*32+32) as 2 c-tiles of 16.
//   MFMA frag layout (verified, m92/m97): lane holds k=(l>>4)*8+j contiguous;
//   C/D: col=lane&15, row=(lane>>4)*4+reg.
// ---------------------------------------------------------------------------
__global__ __launch_bounds__(512)
__attribute__((amdgpu_waves_per_eu(4)))
void attn_kernel(
    const float* __restrict__ qbuf, const float* __restrict__ kbuf,
    const __hip_bfloat16* __restrict__ vT, const float* __restrict__ x,
    const float* __restrict__ gamma_p, float* __restrict__ out)
{
    __shared__ float k_lds[2][MT][CP];              // 8 KB, double-buffered
    __shared__ __hip_bfloat16 v_lds[2][8][2][512];  // 32 KB: [buf][g][ct][16c*32m]
    __shared__ __hip_bfloat16 p_lds[64][32];        // 4 KB: [n][m], slot-swizzled
    __shared__ float pmx[8][64];
    __shared__ float psm[8][64];
    __shared__ float scale_lds[64];

    const int tid = threadIdx.x;
    const int b  = blockIdx.x & 7;       // XCD-aware: one batch per XCD L2
    const int qt = blockIdx.x >> 3;
    const int l  = tid & 63;
    const int g  = tid >> 6;
    const int G  = l >> 4;               // lane quarter 0..3
    const int li = l & 15;

    const float* kg = kbuf + (size_t)b * NPOS * CP;
    const __hip_bfloat16* vTb = vT + (size_t)b * C * NPOS;
    // per-lane V staging source: lane covers c = g*32 + ct*16 + (l>>2),
    // m = (l&3)*8 .. +8  (LDS linear dest = lane*16B = [16c][32m] row-major)
    const __hip_bfloat16* vsrc0 = vTb + (size_t)(g * 32 + (l >> 2)) * NPOS + (l & 3) * 8;

    // q row for column l
    float4 q[8];
    {
        const float4* qp = reinterpret_cast<const float4*>(
            qbuf + ((size_t)b * NPOS + qt * 64 + l) * CP);
        #pragma unroll
        for (int i = 0; i < 8; ++i) q[i] = qp[i];
    }

    f32x4 acc[4][2];                     // [nt][ct]: O^T tile, c=row, n=col
    #pragma unroll
    for (int nt = 0; nt < 4; ++nt)
        #pragma unroll
        for (int ct = 0; ct < 2; ++ct) acc[nt][ct] = (f32x4){0.f, 0.f, 0.f, 0.f};
    float mx = -1e30f, lsum = 0.f;

    // prologue: stage tile 0 into buf 0
    if (g < 4)
        gl_lds16(kg + g * 256 + l * 4, &k_lds[0][0][0] + g * 256);
    gl_lds16(vsrc0,             &v_lds[0][g][0][0]);
    gl_lds16(vsrc0 + 16 * NPOS, &v_lds[0][g][1][0]);

    #pragma unroll 1
    for (int t = 0; t < NT; ++t) {
        const int buf = t & 1;
        wait_vm0();                      // tile t staging arrived
        bar_lds();                       // b1: K/V visible; p_lds reads done

        // issue tile t+1 into other buffer (latency hides under whole tile)
        if (t + 1 < NT) {
            if (g < 4)
                gl_lds16(kg + (size_t)(t + 1) * MT * CP + g * 256 + l * 4,
                         &k_lds[buf ^ 1][0][0] + g * 256);
            gl_lds16(vsrc0 + (t + 1) * 32,             &v_lds[buf ^ 1][g][0][0]);
            gl_lds16(vsrc0 + 16 * NPOS + (t + 1) * 32, &v_lds[buf ^ 1][g][1][0]);
        }

        // ---- QK^T (fp32): wave g computes rows g*4..g*4+3 for column l ----
        float s[4];
        #pragma unroll
        for (int ii = 0; ii < 4; ++ii) {
            const float4* kr = reinterpret_cast<const float4*>(
                &k_lds[buf][g * 4 + ii][0]);          // wave-uniform broadcast
            float sv = 0.f;
            #pragma unroll
            for (int d4 = 0; d4 < 8; ++d4) {
                float4 kv = kr[d4];
                sv = fmaf(q[d4].x, kv.x, sv); sv = fmaf(q[d4].y, kv.y, sv);
                sv = fmaf(q[d4].z, kv.z, sv); sv = fmaf(q[d4].w, kv.w, sv);
            }
            s[ii] = sv;
        }
        pmx[g][l] = fmaxf(fmaxf(s[0], s[1]), fmaxf(s[2], s[3]));
        bar_lds();                       // b2: partial maxes visible

        // ---- softmax (fp32, wave-parallel) ----
        float tm = pmx[0][l];
        #pragma unroll
        for (int gg = 1; gg < 8; ++gg) tm = fmaxf(tm, pmx[gg][l]);
        const float nm = fmaxf(mx, tm);
        const float scale = __expf(mx - nm);
        const float p0 = __expf(s[0] - nm), p1 = __expf(s[1] - nm);
        const float p2 = __expf(s[2] - nm), p3 = __expf(s[3] - nm);
        // P write: row n=l, logical m-slot g, phys slot (g + (l>>3)) & 7
        bf16x4 pv4 = { f2bf(p0), f2bf(p1), f2bf(p2), f2bf(p3) };
        *reinterpret_cast<bf16x4*>(
            reinterpret_cast<char*>(&p_lds[0][0]) + l * 64 + (((g + (l >> 3)) & 7) * 8)) = pv4;
        psm[g][l] = (p0 + p1) + (p2 + p3);
        if (g == 0) scale_lds[l] = scale;
        mx = nm;
        bar_lds();                       // b3: P, psums, scale visible

        float es = psm[0][l];
        #pragma unroll
        for (int gg = 1; gg < 8; ++gg) es += psm[gg][l];
        lsum = lsum * scale + es;

        // ---- PV via MFMA: acc[nt][ct] += V^T_tile(A) * P_tile(B) ----
        // rescale (per-lane scalar: col n = nt*16 + li)
        #pragma unroll
        for (int nt = 0; nt < 4; ++nt) {
            const float scn = scale_lds[nt * 16 + li];
            acc[nt][0] *= scn;
            acc[nt][1] *= scn;
        }
        // A-frags: V^T tile row c=li, k(m) = G*8..+8 contiguous -> one b128
        bf16x8 af[2];
        #pragma unroll
        for (int ct = 0; ct < 2; ++ct)
            af[ct] = *reinterpret_cast<const bf16x8*>(
                reinterpret_cast<const char*>(&v_lds[buf][g][ct][0]) + li * 64 + G * 16);
        // B-frags: P row n = nt*16+li, k(m) = G*8..+8 via 2 swizzled b64
        bf16x8 bfr[4];
        #pragma unroll
        for (int nt = 0; nt < 4; ++nt) {
            const int n = nt * 16 + li;
            const char* prow = reinterpret_cast<const char*>(&p_lds[0][0]) + n * 64;
            bf16x4 blo = *reinterpret_cast<const bf16x4*>(
                prow + ((((2 * G)     + (n >> 3)) & 7) * 8));
            bf16x4 bhi = *reinterpret_cast<const bf16x4*>(
                prow + ((((2 * G + 1) + (n >> 3)) & 7) * 8));
            bfr[nt] = __builtin_shufflevector(blo, bhi, 0,1,2,3,4,5,6,7);
        }
        #pragma unroll
        for (int nt = 0; nt < 4; ++nt) {
            acc[nt][0] = __builtin_amdgcn_mfma_f32_16x16x32_bf16(af[0], bfr[nt], acc[nt][0], 0, 0, 0);
            acc[nt][1] = __builtin_amdgcn_mfma_f32_16x16x32_bf16(af[1], bfr[nt], acc[nt][1], 0, 0, 0);
        }
    }

    // ---- epilogue: out = gamma*(acc/lsum) + x, direct coalesced stores ----
    bar_lds();                           // last tile's scale reads done
    if (g == 0) scale_lds[l] = 1.0f / lsum;
    bar_lds();                           // 1/lsum visible
    const float gamma = *gamma_p;
    const float* xb = x   + (size_t)b * C * NPOS;
    float*       ob = out + (size_t)b * C * NPOS;

    #pragma unroll
    for (int nt = 0; nt < 4; ++nt) {
        const float inv = scale_lds[nt * 16 + li];
        const int n = qt * 64 + nt * 16 + li;
        #pragma unroll
        for (int ct = 0; ct < 2; ++ct) {
            const int c0 = g * 32 + ct * 16 + G * 4;
            #pragma unroll
            for (int r = 0; r < 4; ++r) {
                const size_t idx = (size_t)(c0 + r) * NPOS + n;
                ob[idx] = gamma * acc[nt][ct][r] * inv + xb[idx];
            }
        }
    }
}

extern "C" void kernel_launch(void* const* d_in, const int* in_sizes, int n_in,
                              void* d_out, int out_size, void* d_ws, size_t ws_size,
                              hipStream_t stream) {
    const float* x  = (const float*)d_in[0];
    const float* Wq = (const float*)d_in[1];
    const float* bq = (const float*)d_in[2];
    const float* Wk = (const float*)d_in[3];
    const float* bk = (const float*)d_in[4];
    const float* Wv = (const float*)d_in[5];
    const float* bv = (const float*)d_in[6];
    const float* gamma = (const float*)d_in[7];
    float* out = (float*)d_out;

    // workspace: q 4MB | k 4MB | vT 16.8MB (bf16)
    float* qbuf = (float*)d_ws;
    float* kbuf = qbuf + (size_t)NB * NPOS * CP;
    __hip_bfloat16* vT = (__hip_bfloat16*)(kbuf + (size_t)NB * NPOS * CP);

    qkv_kernel<<<NB * (NPOS / 64), 256, 0, stream>>>(x, Wq, bq, Wk, bk, Wv, bv,
                                                     qbuf, kbuf, vT);
    attn_kernel<<<NB * (NPOS / 64), 512, 0, stream>>>(qbuf, kbuf, vT,
                                                      x, gamma, out);
}

// Round 8
// 312.250 us; speedup vs baseline: 15.2579x; 1.2436x over previous
//
#include <hip/hip_runtime.h>
#include <hip/hip_bf16.h>

// SelfAttention (SAGAN-style): B=8, C=256, N=4096, Cp=32, fp32 in/out.
//   kernel 1 (qkv): x -> qh/ql, kh/kl (B,N,32) bf16 hi/lo pairs,
//                   vT (B,C,N) bf16.
//   kernel 2 (attn): flash attention, fully MFMA:
//     S = kh*qh + kh*ql + kl*qh  (3 mfma, ~fp32-accurate scores)
//     PV via mfma (P bf16, V bf16)  -- R7-proven layouts.
// R8 vs R7: QK^T moved from 128 VALU FMA + 32 ds_read_b128 per thread-tile
//   to 3 MFMA; S stays in D-registers (shfl-based column reduce); all LDS
//   tiles fragment-major (pre-permuted gl_lds src) -> 2-way (free) reads.

constexpr int C  = 256;
constexpr int CP = 32;
constexpr int NPOS = 4096;
constexpr int NB = 8;
constexpr int MT = 32;
constexpr int NT = NPOS / MT;   // 128

typedef __attribute__((ext_vector_type(4))) float  f32x4;
typedef __attribute__((ext_vector_type(4))) short  bf16x4;
typedef __attribute__((ext_vector_type(8))) short  bf16x8;

__device__ __forceinline__ void bar_lds() {
    asm volatile("s_waitcnt lgkmcnt(0)\n\ts_barrier" ::: "memory");
}
__device__ __forceinline__ void wait_vm0() {
    asm volatile("s_waitcnt vmcnt(0)" ::: "memory");
}
__device__ __forceinline__ void gl_lds16(const void* gsrc, void* ldst) {
    typedef const __attribute__((address_space(1))) void* gp_t;
    typedef __attribute__((address_space(3))) void* lp_t;
    __builtin_amdgcn_global_load_lds((gp_t)gsrc, (lp_t)ldst, 16, 0, 0);
}
__device__ __forceinline__ short f2bf(float f) {
    __hip_bfloat16 h = __float2bfloat16(f);
    return __builtin_bit_cast(short, h);
}
__device__ __forceinline__ f32x4 mfma16(bf16x8 a, bf16x8 b, f32x4 c) {
    return __builtin_amdgcn_mfma_f32_16x16x32_bf16(a, b, c, 0, 0, 0);
}

// ---------------------------------------------------------------------------
// QKV projection. Q,K -> bf16 hi/lo [b][n][32]; V -> bf16 transposed [b][c][n].
// ---------------------------------------------------------------------------
__global__ __launch_bounds__(256) void qkv_kernel(
    const float* __restrict__ x,
    const float* __restrict__ Wq, const float* __restrict__ bq,
    const float* __restrict__ Wk, const float* __restrict__ bk,
    const float* __restrict__ Wv, const float* __restrict__ bv,
    __hip_bfloat16* __restrict__ qh, __hip_bfloat16* __restrict__ ql,
    __hip_bfloat16* __restrict__ kh, __hip_bfloat16* __restrict__ kl,
    __hip_bfloat16* __restrict__ vT)
{
    __shared__ float xl[C][64];
    const int tid = threadIdx.x;
    const int b  = blockIdx.x >> 6;
    const int n0 = (blockIdx.x & 63) << 6;

    const float* xb = x + (size_t)b * C * NPOS + n0;
    for (int idx4 = tid; idx4 < C * 16; idx4 += 256) {
        int c = idx4 >> 4, j4 = idx4 & 15;
        float4 gg = *reinterpret_cast<const float4*>(xb + (size_t)c * NPOS + j4 * 4);
        *reinterpret_cast<float4*>(&xl[c][j4 * 4]) = gg;
    }
    __syncthreads();

    const int lane = tid & 63, g = tid >> 6;

    for (int grp = 0; grp < 5; ++grp) {
        const float* Wmat; const float* bias; int r;
        if (grp == 0) {
            if (lane < 32) { Wmat = Wq; bias = bq; r = lane; }
            else           { Wmat = Wk; bias = bk; r = lane - 32; }
        } else {
            Wmat = Wv; bias = bv; r = (grp - 1) * 64 + lane;
        }
        float acc[16];
        const float bval = bias[r];
        #pragma unroll
        for (int jj = 0; jj < 16; ++jj) acc[jj] = bval;

        const float* wrow = Wmat + (size_t)r * C;
        for (int c = 0; c < C; ++c) {
            float w = wrow[c];
            const float4* xv = reinterpret_cast<const float4*>(&xl[c][g * 16]);
            #pragma unroll
            for (int j4 = 0; j4 < 4; ++j4) {
                float4 xq = xv[j4];
                acc[j4*4+0] = fmaf(w, xq.x, acc[j4*4+0]);
                acc[j4*4+1] = fmaf(w, xq.y, acc[j4*4+1]);
                acc[j4*4+2] = fmaf(w, xq.z, acc[j4*4+2]);
                acc[j4*4+3] = fmaf(w, xq.w, acc[j4*4+3]);
            }
        }
        if (grp == 0) {
            __hip_bfloat16* hb = (lane < 32) ? qh : kh;
            __hip_bfloat16* lb = (lane < 32) ? ql : kl;
            const size_t base = (size_t)b * NPOS + n0 + g * 16;
            #pragma unroll
            for (int jj = 0; jj < 16; ++jj) {
                const float v = acc[jj];
                __hip_bfloat16 h = __float2bfloat16(v);
                __hip_bfloat16 lo = __float2bfloat16(v - __bfloat162float(h));
                hb[(base + jj) * CP + r] = h;
                lb[(base + jj) * CP + r] = lo;
            }
        } else {
            bf16x8 w0, w1;
            #pragma unroll
            for (int jj = 0; jj < 8; ++jj) { w0[jj] = f2bf(acc[jj]); w1[jj] = f2bf(acc[8 + jj]); }
            __hip_bfloat16* vp = vT + ((size_t)b * C + r) * NPOS + n0 + g * 16;
            *reinterpret_cast<bf16x8*>(vp)     = w0;
            *reinterpret_cast<bf16x8*>(vp + 8) = w1;
        }
    }
}

// ---------------------------------------------------------------------------
// Flash attention, fully-MFMA.
//   512 threads (8 waves), block = 64 queries x 256 channels, grid 512.
//   Wave g: S-subtile (mi=g>>2, nj=g&3); PV channels [g*32, g*32+32).
//   Frag layouts (verified): A/B lane holds k=(l>>4)*8+j contiguous;
//   C/D col=lane&15, row=(lane>>4)*4+reg.
// ---------------------------------------------------------------------------
__global__ __launch_bounds__(512)
__attribute__((amdgpu_waves_per_eu(4)))
void attn_kernel(
    const __hip_bfloat16* __restrict__ qh, const __hip_bfloat16* __restrict__ ql,
    const __hip_bfloat16* __restrict__ kh, const __hip_bfloat16* __restrict__ kl,
    const __hip_bfloat16* __restrict__ vT, const float* __restrict__ x,
    const float* __restrict__ gamma_p, float* __restrict__ out)
{
    // fragment-major chunk layouts (16B chunks):
    //   k_lds[buf][h]: chunk = G*32 + mi*16 + li   (128 chunks = 2KB)
    //   v_lds[buf][g][ct]: chunk = G*16 + li        (64 chunks = 1KB)
    __shared__ __align__(16) __hip_bfloat16 k_lds[2][2][1024];   // 8 KB
    __shared__ __align__(16) __hip_bfloat16 v_lds[2][8][2][512]; // 32 KB
    __shared__ __align__(16) __hip_bfloat16 p_lds[2048];         // 4 KB [mslot][n^mslot]
    __shared__ float pmx[2][64];
    __shared__ float psm[2][64];
    __shared__ float mxs[64], lsums[64], scale_lds[64], nm_lds[64];

    const int tid = threadIdx.x;
    const int b  = blockIdx.x & 7;       // XCD-aware: one batch per XCD L2
    const int qt = blockIdx.x >> 3;
    const int l  = tid & 63;
    const int g  = tid >> 6;
    const int G  = l >> 4;
    const int li = l & 15;
    const int mi = g >> 2, nj = g & 3;

    const __hip_bfloat16* khb = kh + (size_t)b * NPOS * CP;
    const __hip_bfloat16* klb = kl + (size_t)b * NPOS * CP;
    const __hip_bfloat16* vTb = vT + (size_t)b * C * NPOS;

    if (tid < 64) { mxs[tid] = -1e30f; lsums[tid] = 0.f; }

    // Q fragments (persistent registers): lane holds Q[n=nj*16+li][k=G*8..+8]
    bf16x8 qhf, qlf;
    {
        const size_t qoff = ((size_t)b * NPOS + qt * 64 + nj * 16 + li) * CP + G * 8;
        qhf = *reinterpret_cast<const bf16x8*>(qh + qoff);
        qlf = *reinterpret_cast<const bf16x8*>(ql + qoff);
    }

    // staging source offsets (element units)
    //   K: dest chunk d=(g&1)*64+l -> Gd=d>>5, mid=(d>>4)&1, lid=d&15
    const int kd   = ((g & 1) << 6) | l;
    const int koff = ((kd >> 4) & 1) * 16 * CP + (kd & 15) * CP + (kd >> 5) * 8;
    //   V: dest chunk d=l -> Gd=l>>4, lid=l&15
    const size_t voff0 = (size_t)(g * 32 + li) * NPOS + G * 8;          // ct=0
    const size_t voff1 = (size_t)(g * 32 + 16 + li) * NPOS + G * 8;     // ct=1

    f32x4 acc[4][2];                     // [nt][ct]: O^T tile, c=row, n=col
    #pragma unroll
    for (int nt = 0; nt < 4; ++nt)
        #pragma unroll
        for (int ct = 0; ct < 2; ++ct) acc[nt][ct] = (f32x4){0.f, 0.f, 0.f, 0.f};

    // prologue: stage tile 0 into buf 0
    if (g < 4) {
        const __hip_bfloat16* ks = (g < 2) ? khb : klb;
        gl_lds16(ks + koff, &k_lds[0][g >> 1][(g & 1) * 512]);
    }
    gl_lds16(vTb + voff0, &v_lds[0][g][0][0]);
    gl_lds16(vTb + voff1, &v_lds[0][g][1][0]);

    #pragma unroll 1
    for (int t = 0; t < NT; ++t) {
        const int buf = t & 1;
        wait_vm0();
        bar_lds();                       // b1: tile t staged & visible

        // issue tile t+1
        if (t + 1 < NT) {
            if (g < 4) {
                const __hip_bfloat16* ks = (g < 2) ? khb : klb;
                gl_lds16(ks + (size_t)(t + 1) * MT * CP + koff,
                         &k_lds[buf ^ 1][g >> 1][(g & 1) * 512]);
            }
            gl_lds16(vTb + voff0 + (t + 1) * MT, &v_lds[buf ^ 1][g][0][0]);
            gl_lds16(vTb + voff1 + (t + 1) * MT, &v_lds[buf ^ 1][g][1][0]);
        }

        // ---- S = K.Q^T via 3 MFMA (hi/lo) ----
        const int kfo = G * 256 + mi * 128 + li * 8;   // frag-major offset
        bf16x8 khf = *reinterpret_cast<const bf16x8*>(&k_lds[buf][0][0] + kfo);
        bf16x8 klf = *reinterpret_cast<const bf16x8*>(&k_lds[buf][1][0] + kfo);
        f32x4 sacc = (f32x4){0.f, 0.f, 0.f, 0.f};
        sacc = mfma16(khf, qhf, sacc);
        sacc = mfma16(khf, qlf, sacc);
        sacc = mfma16(klf, qhf, sacc);
        // lane holds S[m = mi*16 + 4G + r][n = nj*16 + li]

        // column(-n) partial max over this wave's 16 m-rows
        float m4 = fmaxf(fmaxf(sacc[0], sacc[1]), fmaxf(sacc[2], sacc[3]));
        m4 = fmaxf(m4, __shfl_xor(m4, 16));
        m4 = fmaxf(m4, __shfl_xor(m4, 32));
        if (G == 0) pmx[mi][nj * 16 + li] = m4;
        bar_lds();                       // b2: partial maxes visible

        // owner (col n = g*16 + l, waves 0-3 lanes 0-15): new max + scale
        if (g < 4 && l < 16) {
            const int n = g * 16 + l;
            const float old = mxs[n];
            const float nm = fmaxf(old, fmaxf(pmx[0][n], pmx[1][n]));
            scale_lds[n] = __expf(old - nm);
            nm_lds[n] = nm;
            mxs[n] = nm;
        }
        bar_lds();                       // b3: nm/scale visible

        // ---- P = exp(S - nm), write bf16 frags + partial sums ----
        {
            const int sn = nj * 16 + li;
            const float nm = nm_lds[sn];
            const float p0 = __expf(sacc[0] - nm), p1 = __expf(sacc[1] - nm);
            const float p2 = __expf(sacc[2] - nm), p3 = __expf(sacc[3] - nm);
            const int mslot = mi * 4 + G;
            bf16x4 pv4 = { f2bf(p0), f2bf(p1), f2bf(p2), f2bf(p3) };
            *reinterpret_cast<bf16x4*>(p_lds + mslot * 256 + ((sn ^ mslot) * 4)) = pv4;
            float ps = (p0 + p1) + (p2 + p3);
            ps += __shfl_xor(ps, 16);
            ps += __shfl_xor(ps, 32);
            if (G == 0) psm[mi][sn] = ps;
        }
        bar_lds();                       // b4: P + psums visible

        // owner: running denom
        if (g < 4 && l < 16) {
            const int n = g * 16 + l;
            lsums[n] = lsums[n] * scale_lds[n] + psm[0][n] + psm[1][n];
        }

        // ---- PV via MFMA: acc[nt][ct] += V^T(A) * P(B) ----
        #pragma unroll
        for (int nt = 0; nt < 4; ++nt) {
            const float scn = scale_lds[nt * 16 + li];
            acc[nt][0] *= scn;
            acc[nt][1] *= scn;
        }
        bf16x8 af[2];
        #pragma unroll
        for (int ct = 0; ct < 2; ++ct)
            af[ct] = *reinterpret_cast<const bf16x8*>(
                &v_lds[buf][g][ct][0] + G * 128 + li * 8);
        bf16x8 bfr[4];
        #pragma unroll
        for (int nt = 0; nt < 4; ++nt) {
            const int n = nt * 16 + li;
            bf16x4 blo = *reinterpret_cast<const bf16x4*>(
                p_lds + (2 * G) * 256 + ((n ^ (2 * G)) * 4));
            bf16x4 bhi = *reinterpret_cast<const bf16x4*>(
                p_lds + (2 * G + 1) * 256 + ((n ^ (2 * G + 1)) * 4));
            bfr[nt] = __builtin_shufflevector(blo, bhi, 0,1,2,3,4,5,6,7);
        }
        #pragma unroll
        for (int nt = 0; nt < 4; ++nt) {
            acc[nt][0] = mfma16(af[0], bfr[nt], acc[nt][0]);
            acc[nt][1] = mfma16(af[1], bfr[nt], acc[nt][1]);
        }
    }

    // ---- epilogue: out = gamma*(acc/lsum) + x, direct coalesced stores ----
    bar_lds();                           // final lsums visible
    const float gamma = *gamma_p;
    const float* xb = x   + (size_t)b * C * NPOS;
    float*       ob = out + (size_t)b * C * NPOS;

    #pragma unroll
    for (int nt = 0; nt < 4; ++nt) {
        const float inv = 1.0f / lsums[nt * 16 + li];
        const int n = qt * 64 + nt * 16 + li;
        #pragma unroll
        for (int ct = 0; ct < 2; ++ct) {
            const int c0 = g * 32 + ct * 16 + G * 4;
            #pragma unroll
            for (int r = 0; r < 4; ++r) {
                const size_t idx = (size_t)(c0 + r) * NPOS + n;
                ob[idx] = gamma * acc[nt][ct][r] * inv + xb[idx];
            }
        }
    }
}

extern "C" void kernel_launch(void* const* d_in, const int* in_sizes, int n_in,
                              void* d_out, int out_size, void* d_ws, size_t ws_size,
                              hipStream_t stream) {
    const float* x  = (const float*)d_in[0];
    const float* Wq = (const float*)d_in[1];
    const float* bq = (const float*)d_in[2];
    const float* Wk = (const float*)d_in[3];
    const float* bk = (const float*)d_in[4];
    const float* Wv = (const float*)d_in[5];
    const float* bv = (const float*)d_in[6];
    const float* gamma = (const float*)d_in[7];
    float* out = (float*)d_out;

    // workspace: qh|ql|kh|kl (2MB each bf16) | vT 16.8MB bf16  = 24.8MB
    const size_t qk_n = (size_t)NB * NPOS * CP;
    __hip_bfloat16* qhb = (__hip_bfloat16*)d_ws;
    __hip_bfloat16* qlb = qhb + qk_n;
    __hip_bfloat16* khb = qlb + qk_n;
    __hip_bfloat16* klb = khb + qk_n;
    __hip_bfloat16* vT  = klb + qk_n;

    qkv_kernel<<<NB * (NPOS / 64), 256, 0, stream>>>(x, Wq, bq, Wk, bk, Wv, bv,
                                                     qhb, qlb, khb, klb, vT);
    attn_kernel<<<NB * (NPOS / 64), 512, 0, stream>>>(qhb, qlb, khb, klb, vT,
                                                      x, gamma, out);
}